// Round 2
// 545.568 us; speedup vs baseline: 1.0629x; 1.0629x over previous
//
#include <hip/hip_runtime.h>
#include <stdint.h>

#define NGRAPHS 4096
#define NNODES  524288
#define DIN     128
#define DOUT    256
#define TILE    512          // rows per seg_sum block (NNODES % TILE == 0)
#define G2      8            // graphs per seg_mm block

// Key identity: mean(x W + b) over a segment = (mean x) W + b.
// Pipeline (workspace = float sums[2][NGRAPHS][DIN], 4 MB):
//   1. zero_ws   : clear accumulator
//   2. seg_sum   : fixed 512-row tiles (load-balanced), segment column-sums,
//                  direct store for tile-interior segments, atomicAdd at
//                  tile-boundary segments only
//   3. seg_mm    : mean + 1x128 @ 128x256 + bias, 8 graphs/block to amortize
//                  W reads; empty graphs (n==0) write exact zeros (reference
//                  divides a zero sum by max(count,1) -> 0, bias never added)

__global__ __launch_bounds__(256)
void zero_ws(float4* __restrict__ ws) {
    ws[(size_t)blockIdx.x * 256 + threadIdx.x] = make_float4(0.f, 0.f, 0.f, 0.f);
}

__global__ __launch_bounds__(256, 8)
void seg_sum_kernel(const float* __restrict__ x_a, const int* __restrict__ ptr_a,
                    const float* __restrict__ x_b, const int* __restrict__ ptr_b,
                    float* __restrict__ sums) {
    const int t = blockIdx.y;
    const float* __restrict__ x   = t ? x_b  : x_a;
    const int*   __restrict__ ptr = t ? ptr_b : ptr_a;
    float* __restrict__ seg = sums + (size_t)t * NGRAPHS * DIN;

    const int r0 = blockIdx.x * TILE;
    const int r1 = r0 + TILE;                 // NNODES % TILE == 0

    const int tid  = threadIdx.x;
    const int slot = tid & 31;                // 16B chunk of the 512B row
    const int r    = tid >> 5;                // row-within-8 group

    __shared__ float red[8][DIN];             // 4 KB

    // g = graph containing row r0: last g with ptr[g] <= r0 (skips empty dups)
    int lo = 0, hi = NGRAPHS;                 // first idx with ptr[idx] > r0
    while (lo < hi) {
        int mid = (lo + hi) >> 1;
        if (ptr[mid] <= r0) lo = mid + 1; else hi = mid;
    }
    int g = lo - 1;

    const float* __restrict__ xs = x + (size_t)slot * 4;

    for (;;) {
        const int ss = ptr[g];
        const int ee = ptr[g + 1];
        const int a  = ss > r0 ? ss : r0;
        const int b  = ee < r1 ? ee : r1;

        if (b > a) {
            float4 acc = make_float4(0.f, 0.f, 0.f, 0.f);
            for (int i = a + r; i < b; i += 8) {
                const float4 v = *(const float4*)(xs + (size_t)i * DIN);
                acc.x += v.x; acc.y += v.y; acc.z += v.z; acc.w += v.w;
            }
            red[r][slot * 4 + 0] = acc.x;
            red[r][slot * 4 + 1] = acc.y;
            red[r][slot * 4 + 2] = acc.z;
            red[r][slot * 4 + 3] = acc.w;
            __syncthreads();
            if (tid < DIN) {
                float v = 0.f;
#pragma unroll
                for (int rr = 0; rr < 8; ++rr) v += red[rr][tid];
                float* dst = seg + (size_t)g * DIN + tid;
                if (ss >= r0 && ee <= r1) *dst = v;          // interior segment
                else                      atomicAdd(dst, v); // boundary segment
            }
            __syncthreads();                  // red reused next segment
        }
        if (ee >= r1) break;
        ++g;
    }
}

__global__ __launch_bounds__(256)
void seg_mm_kernel(const float* __restrict__ W_a, const float* __restrict__ b_a,
                   const int* __restrict__ ptr_a,
                   const float* __restrict__ W_b, const float* __restrict__ b_b,
                   const int* __restrict__ ptr_b,
                   const float* __restrict__ sums, float* __restrict__ out) {
    const int t = blockIdx.y;
    const float* __restrict__ W    = t ? W_b  : W_a;
    const float* __restrict__ bias = t ? b_b  : b_a;
    const int*   __restrict__ ptr  = t ? ptr_b : ptr_a;
    const float* __restrict__ seg  = sums + (size_t)t * NGRAPHS * DIN;

    const int g0  = blockIdx.x * G2;
    const int tid = threadIdx.x;

    __shared__ __align__(16) float mean[G2][DIN];   // 4 KB
    __shared__ float cnt[G2];

    if (tid < G2) {
        int n = ptr[g0 + tid + 1] - ptr[g0 + tid];
        cnt[tid] = (float)(n > 0 ? n : 1);
    }
    __syncthreads();
    for (int idx = tid; idx < G2 * DIN; idx += 256) {
        int gg = idx >> 7, k = idx & 127;
        mean[gg][k] = seg[(size_t)(g0 + gg) * DIN + k] / cnt[gg];
    }
    __syncthreads();

    float acc[G2];
#pragma unroll
    for (int gg = 0; gg < G2; ++gg) acc[gg] = 0.f;

    const float* __restrict__ wcol = W + tid;       // column tid, stride DOUT
    for (int k = 0; k < DIN; k += 4) {
        float w0 = wcol[(size_t)(k + 0) * DOUT];
        float w1 = wcol[(size_t)(k + 1) * DOUT];
        float w2 = wcol[(size_t)(k + 2) * DOUT];
        float w3 = wcol[(size_t)(k + 3) * DOUT];
#pragma unroll
        for (int gg = 0; gg < G2; ++gg) {
            const float4 m = *(const float4*)&mean[gg][k];
            acc[gg] += m.x * w0 + m.y * w1 + m.z * w2 + m.w * w3;
        }
    }

    const float bv = bias[tid];
#pragma unroll
    for (int gg = 0; gg < G2; ++gg) {
        const int g = g0 + gg;
        const int n = ptr[g + 1] - ptr[g];
        out[(size_t)g * (2 * DOUT) + t * DOUT + tid] = (n > 0) ? acc[gg] + bv : 0.f;
    }
}

// ---------------- fallback (original single-kernel path) ----------------
__global__ __launch_bounds__(256)
void seg_encode_fallback(const float* __restrict__ x_a, const float* __restrict__ W_a,
                         const float* __restrict__ b_a, const int* __restrict__ ptr_a,
                         const float* __restrict__ x_b, const float* __restrict__ W_b,
                         const float* __restrict__ b_b, const int* __restrict__ ptr_b,
                         float* __restrict__ out) {
    const int g   = blockIdx.x;
    const int t   = blockIdx.y;
    const int tid = threadIdx.x;

    const float* __restrict__ x    = t ? x_b  : x_a;
    const float* __restrict__ W    = t ? W_b  : W_a;
    const float* __restrict__ bias = t ? b_b  : b_a;
    const int*   __restrict__ ptr  = t ? ptr_b : ptr_a;

    const int s = ptr[g];
    const int e = ptr[g + 1];
    const int n = e - s;

    float* __restrict__ orow = out + (size_t)g * (2 * DOUT) + t * DOUT;
    if (n == 0) { orow[tid] = 0.0f; return; }

    __shared__ float red[8][DIN];
    __shared__ float mean[DIN];

    const int slot = tid & 31;
    const int r    = tid >> 5;
    float4 acc = make_float4(0.f, 0.f, 0.f, 0.f);
    const float* __restrict__ xs = x + (size_t)slot * 4;
    for (int i = s + r; i < e; i += 8) {
        float4 v = *(const float4*)(xs + (size_t)i * DIN);
        acc.x += v.x; acc.y += v.y; acc.z += v.z; acc.w += v.w;
    }
    red[r][slot * 4 + 0] = acc.x;
    red[r][slot * 4 + 1] = acc.y;
    red[r][slot * 4 + 2] = acc.z;
    red[r][slot * 4 + 3] = acc.w;
    __syncthreads();
    if (tid < DIN) {
        float sum = 0.0f;
#pragma unroll
        for (int rr = 0; rr < 8; ++rr) sum += red[rr][tid];
        mean[tid] = sum * (1.0f / (float)n);
    }
    __syncthreads();
    float o = bias[tid];
    const float* __restrict__ wcol = W + tid;
#pragma unroll 8
    for (int k = 0; k < DIN; ++k) o += mean[k] * wcol[(size_t)k * DOUT];
    orow[tid] = o;
}

extern "C" void kernel_launch(void* const* d_in, const int* in_sizes, int n_in,
                              void* d_out, int out_size, void* d_ws, size_t ws_size,
                              hipStream_t stream) {
    const float* x_a  = (const float*)d_in[0];
    const float* W_a  = (const float*)d_in[1];
    const float* b_a  = (const float*)d_in[2];
    const float* x_b  = (const float*)d_in[3];
    const float* W_b  = (const float*)d_in[4];
    const float* b_b  = (const float*)d_in[5];
    const int*   ptr_a = (const int*)d_in[6];
    const int*   ptr_b = (const int*)d_in[7];
    float* out = (float*)d_out;

    const size_t ws_needed = (size_t)2 * NGRAPHS * DIN * sizeof(float); // 4 MB

    if (d_ws == nullptr || ws_size < ws_needed) {
        dim3 grid(NGRAPHS, 2);
        seg_encode_fallback<<<grid, 256, 0, stream>>>(x_a, W_a, b_a, ptr_a,
                                                      x_b, W_b, b_b, ptr_b, out);
        return;
    }

    float* sums = (float*)d_ws;

    zero_ws<<<(2 * NGRAPHS * DIN) / (256 * 4), 256, 0, stream>>>((float4*)sums);

    dim3 grid1(NNODES / TILE, 2);
    seg_sum_kernel<<<grid1, 256, 0, stream>>>(x_a, ptr_a, x_b, ptr_b, sums);

    dim3 grid2(NGRAPHS / G2, 2);
    seg_mm_kernel<<<grid2, 256, 0, stream>>>(W_a, b_a, ptr_a, W_b, b_b, ptr_b,
                                             sums, out);
}